// Round 1
// baseline (1726.314 us; speedup 1.0000x reference)
//
#include <hip/hip_runtime.h>

// Problem constants (fixed by the reference): B=4, S=2048, D=DK=1024.
constexpr int Bc  = 4;
constexpr int Sc  = 2048;
constexpr int Dc  = 1024;
constexpr int DKc = 1024;
constexpr long BSc = (long)Bc * Sc;      // 8192 flattened rows of x

typedef __attribute__((ext_vector_type(8))) __bf16 bf16x8;
typedef __attribute__((ext_vector_type(4))) float  floatx4;

__device__ inline __bf16 f2bf(float f) {
  unsigned u = __builtin_bit_cast(unsigned, f);
  u = (u + 0x7FFFu + ((u >> 16) & 1u)) >> 16;      // RNE
  unsigned short s = (unsigned short)u;
  return __builtin_bit_cast(__bf16, s);
}
__device__ inline float bf2f(__bf16 h) {
  unsigned u = ((unsigned)__builtin_bit_cast(unsigned short, h)) << 16;
  return __builtin_bit_cast(float, u);
}

// ---------------------------------------------------------------------------
// x (fp32) -> xhi + xlo (bf16 split). Grid covers exactly B*S*D elements.
// ---------------------------------------------------------------------------
__global__ __launch_bounds__(256) void cast_split(const float* __restrict__ in,
                                                  __bf16* __restrict__ hi,
                                                  __bf16* __restrict__ lo) {
  long i = (long)blockIdx.x * 256 + threadIdx.x;
  float f = in[i];
  __bf16 h = f2bf(f);
  hi[i] = h;
  lo[i] = f2bf(f - bf2f(h));
}

// ---------------------------------------------------------------------------
// W [D][DK] fp32 -> Wt hi/lo [DK][D] bf16 (transposed split). 32x32 LDS tile.
// ---------------------------------------------------------------------------
__global__ __launch_bounds__(256) void transpose_split(const float* __restrict__ in,
                                                       __bf16* __restrict__ hi,
                                                       __bf16* __restrict__ lo) {
  __shared__ float tile[32][33];
  int xI = blockIdx.x * 32 + threadIdx.x;
  int yI = blockIdx.y * 32 + threadIdx.y;
#pragma unroll
  for (int j = 0; j < 32; j += 8)
    tile[threadIdx.y + j][threadIdx.x] = in[(long)(yI + j) * DKc + xI];
  __syncthreads();
  int xO = blockIdx.y * 32 + threadIdx.x;
  int yO = blockIdx.x * 32 + threadIdx.y;
#pragma unroll
  for (int j = 0; j < 32; j += 8) {
    float v = tile[threadIdx.x][threadIdx.y + j];
    long idx = (long)(yO + j) * Dc + xO;
    __bf16 h = f2bf(v);
    hi[idx] = h;
    lo[idx] = f2bf(v - bf2f(h));
  }
}

// ---------------------------------------------------------------------------
// NT MFMA GEMM: C[M][N] = A[M][K] * Bt[N][K]^T, both row-major bf16.
// MODE_QK: split compute (3 MFMAs), store bf16 hi+lo       (M=8192,N=1024,K=1024)
// MODE_V : plain bf16, TRANSPOSED store -> Vt[b][n][seq]   (M=8192,N=1024,K=1024)
// MODE_S : split compute, fp32 store with scale, z=B       (M=2048,N=2048,K=1024)
// MODE_PV: plain bf16, fp32 store, z=B                     (M=2048,N=1024,K=2048)
// Block = 256 (4 waves); tile 64x64; wave w -> rows [16w,16w+16), 4 n-subtiles.
// Fragment layout (m89/m91-verified): A[m=lane&15][k=(lane>>4)*8+j],
// B symmetric on n; D: col=lane&15, row=(lane>>4)*4+reg.
// ---------------------------------------------------------------------------
enum { MODE_QK = 0, MODE_V = 1, MODE_S = 2, MODE_PV = 3 };

template <int MODE>
__global__ __launch_bounds__(256) void gemm_nt(
    const __bf16* __restrict__ Ahi, const __bf16* __restrict__ Alo,
    const __bf16* __restrict__ Bhi, const __bf16* __restrict__ Blo,
    float* __restrict__ Cf, __bf16* __restrict__ Chi, __bf16* __restrict__ Clo,
    float scale) {
  constexpr bool SPLIT = (MODE == MODE_QK || MODE == MODE_S);
  constexpr int  M = (MODE == MODE_S || MODE == MODE_PV) ? Sc : (int)BSc;
  constexpr int  N = (MODE == MODE_S) ? Sc : DKc;
  constexpr int  K = (MODE == MODE_PV) ? Sc : Dc;
  constexpr long aBatch = (MODE == MODE_S) ? (long)Sc * DKc
                        : (MODE == MODE_PV) ? (long)Sc * Sc : 0;
  constexpr long bBatch = (MODE == MODE_S) ? (long)Sc * DKc
                        : (MODE == MODE_PV) ? (long)DKc * Sc : 0;
  constexpr long cBatch = (MODE == MODE_S) ? (long)Sc * Sc
                        : (MODE == MODE_PV) ? (long)Sc * DKc : 0;

  const int b    = blockIdx.z;
  const int wave = threadIdx.x >> 6;
  const int lane = threadIdx.x & 63;
  const int frow = lane & 15;
  const int koff = (lane >> 4) * 8;
  const int m0 = blockIdx.y * 64 + wave * 16;
  const int n0 = blockIdx.x * 64;

  const __bf16* aH = Ahi + (long)b * aBatch + (long)(m0 + frow) * K + koff;
  const __bf16* aL = SPLIT ? Alo + (long)b * aBatch + (long)(m0 + frow) * K + koff : nullptr;
  const __bf16* bH = Bhi + (long)b * bBatch + (long)(n0 + frow) * K + koff;
  const __bf16* bL = SPLIT ? Blo + (long)b * bBatch + (long)(n0 + frow) * K + koff : nullptr;

  floatx4 acc[4];
  const floatx4 zero = {0.f, 0.f, 0.f, 0.f};
#pragma unroll
  for (int i = 0; i < 4; ++i) acc[i] = zero;

  for (int k = 0; k < K; k += 32) {
    bf16x8 ah = *(const bf16x8*)(aH + k);
    bf16x8 al;
    if constexpr (SPLIT) al = *(const bf16x8*)(aL + k);
#pragma unroll
    for (int nt = 0; nt < 4; ++nt) {
      bf16x8 bh = *(const bf16x8*)(bH + (long)nt * 16 * K + k);
      acc[nt] = __builtin_amdgcn_mfma_f32_16x16x32_bf16(ah, bh, acc[nt], 0, 0, 0);
      if constexpr (SPLIT) {
        bf16x8 bl = *(const bf16x8*)(bL + (long)nt * 16 * K + k);
        acc[nt] = __builtin_amdgcn_mfma_f32_16x16x32_bf16(ah, bl, acc[nt], 0, 0, 0);
        acc[nt] = __builtin_amdgcn_mfma_f32_16x16x32_bf16(al, bh, acc[nt], 0, 0, 0);
      }
    }
  }

  const int crow0 = (lane >> 4) * 4;
  const int ccol  = lane & 15;
#pragma unroll
  for (int nt = 0; nt < 4; ++nt) {
    int cn = n0 + nt * 16 + ccol;
#pragma unroll
    for (int r = 0; r < 4; ++r) {
      int cm = m0 + crow0 + r;
      float v = acc[nt][r] * scale;
      if constexpr (MODE == MODE_S || MODE == MODE_PV) {
        Cf[(long)b * cBatch + (long)cm * N + cn] = v;
      } else if constexpr (MODE == MODE_QK) {
        long idx = (long)cm * N + cn;
        __bf16 h = f2bf(v);
        Chi[idx] = h;
        Clo[idx] = f2bf(v - bf2f(h));
      } else {  // MODE_V: store transposed Vt[b][n][seq]
        int bb = cm >> 11;        // / S
        int sq = cm & (Sc - 1);   // % S
        Chi[(long)bb * N * Sc + (long)cn * Sc + sq] = f2bf(v);
      }
    }
  }
}

// ---------------------------------------------------------------------------
// Column softmax over q (axis=1) of scores[b][q][k], online max/sum.
// Block 256 = 32 columns x 8 q-groups; grid (S/32, B) = 256 blocks.
// ---------------------------------------------------------------------------
__global__ __launch_bounds__(256) void softmax_col(const float* __restrict__ sc,
                                                   __bf16* __restrict__ attn) {
  __shared__ float sm[8][32], ss[8][32];
  const int b  = blockIdx.y;
  const int kk = threadIdx.x & 31;
  const int g  = threadIdx.x >> 5;
  const int k  = blockIdx.x * 32 + kk;
  const float* base = sc + (long)b * Sc * Sc + k;
  const int q0 = g * (Sc / 8), q1 = q0 + (Sc / 8);

  float m = -3.0e38f, s = 0.f;
  for (int q = q0; q < q1; ++q) {
    float v = base[(long)q * Sc];
    float mn = fmaxf(m, v);
    s = s * __expf(m - mn) + __expf(v - mn);
    m = mn;
  }
  sm[g][kk] = m;
  ss[g][kk] = s;
  __syncthreads();
  if (g == 0) {
    float M = sm[0][kk], S = ss[0][kk];
#pragma unroll
    for (int j = 1; j < 8; ++j) {
      float mj = sm[j][kk], sj = ss[j][kk];
      float mn = fmaxf(M, mj);
      S = S * __expf(M - mn) + sj * __expf(mj - mn);
      M = mn;
    }
    sm[0][kk] = M;
    ss[0][kk] = 1.0f / S;
  }
  __syncthreads();
  const float M = sm[0][kk], inv = ss[0][kk];
  __bf16* ab = attn + (long)b * Sc * Sc + k;
  for (int q = q0; q < q1; ++q) {
    float v = base[(long)q * Sc];
    ab[(long)q * Sc] = f2bf(__expf(v - M) * inv);
  }
}

// ---------------------------------------------------------------------------
extern "C" void kernel_launch(void* const* d_in, const int* in_sizes, int n_in,
                              void* d_out, int out_size, void* d_ws, size_t ws_size,
                              hipStream_t stream) {
  const float* x  = (const float*)d_in[0];
  const float* WQ = (const float*)d_in[1];
  const float* WK = (const float*)d_in[2];
  const float* WV = (const float*)d_in[3];
  float* out = (float*)d_out;
  char* ws = (char*)d_ws;
  const long MB = 1024L * 1024L;

  // Workspace layout (peak 188 MB). attn reuses the x region (x dead by then).
  __bf16* xhi  = (__bf16*)(ws + 0 * MB);     // 16 MB
  __bf16* xlo  = (__bf16*)(ws + 16 * MB);    // 16 MB
  __bf16* wqhi = (__bf16*)(ws + 32 * MB);    // 2 MB each
  __bf16* wqlo = (__bf16*)(ws + 34 * MB);
  __bf16* wkhi = (__bf16*)(ws + 36 * MB);
  __bf16* wklo = (__bf16*)(ws + 38 * MB);
  __bf16* wvhi = (__bf16*)(ws + 40 * MB);
  __bf16* wvlo = (__bf16*)(ws + 42 * MB);
  __bf16* qhi  = (__bf16*)(ws + 44 * MB);    // 16 MB each
  __bf16* qlo  = (__bf16*)(ws + 60 * MB);
  __bf16* khi  = (__bf16*)(ws + 76 * MB);
  __bf16* klo  = (__bf16*)(ws + 92 * MB);
  __bf16* vt   = (__bf16*)(ws + 108 * MB);   // 16 MB, [B][DK][S]
  float*  scs  = (float*)(ws + 124 * MB);    // 64 MB, [B][S][S]
  __bf16* attn = (__bf16*)(ws + 0 * MB);     // 32 MB, reuses x region

  cast_split<<<(int)((BSc * Dc) / 256), 256, 0, stream>>>(x, xhi, xlo);
  dim3 tb(32, 8);
  transpose_split<<<dim3(32, 32), tb, 0, stream>>>(WQ, wqhi, wqlo);
  transpose_split<<<dim3(32, 32), tb, 0, stream>>>(WK, wkhi, wklo);
  transpose_split<<<dim3(32, 32), tb, 0, stream>>>(WV, wvhi, wvlo);

  dim3 gProj(DKc / 64, BSc / 64, 1);
  gemm_nt<MODE_QK><<<gProj, 256, 0, stream>>>(xhi, xlo, wqhi, wqlo, nullptr, qhi, qlo, 1.0f);
  gemm_nt<MODE_QK><<<gProj, 256, 0, stream>>>(xhi, xlo, wkhi, wklo, nullptr, khi, klo, 1.0f);
  gemm_nt<MODE_V ><<<gProj, 256, 0, stream>>>(xhi, nullptr, wvhi, nullptr, nullptr, vt, nullptr, 1.0f);

  dim3 gS(Sc / 64, Sc / 64, Bc);
  gemm_nt<MODE_S><<<gS, 256, 0, stream>>>(qhi, qlo, khi, klo, scs, nullptr, nullptr, 0.03125f);

  softmax_col<<<dim3(Sc / 32, Bc), 256, 0, stream>>>(scs, attn);

  dim3 gPV(DKc / 64, Sc / 64, Bc);
  gemm_nt<MODE_PV><<<gPV, 256, 0, stream>>>(attn, nullptr, vt, nullptr, out, nullptr, nullptr, 1.0f);
}

// Round 2
// 459.237 us; speedup vs baseline: 3.7591x; 3.7591x over previous
//
#include <hip/hip_runtime.h>

// Problem constants (fixed by the reference): B=4, S=2048, D=DK=1024.
constexpr int Bc  = 4;
constexpr int Sc  = 2048;
constexpr int Dc  = 1024;
constexpr int DKc = 1024;
constexpr long BSc = (long)Bc * Sc;      // 8192 flattened rows of x

typedef __attribute__((ext_vector_type(8))) __bf16 bf16x8;
typedef __attribute__((ext_vector_type(4))) float  floatx4;

__device__ inline __bf16 f2bf(float f) {
  unsigned u = __builtin_bit_cast(unsigned, f);
  u = (u + 0x7FFFu + ((u >> 16) & 1u)) >> 16;      // RNE
  unsigned short s = (unsigned short)u;
  return __builtin_bit_cast(__bf16, s);
}
__device__ inline float bf2f(__bf16 h) {
  unsigned u = ((unsigned)__builtin_bit_cast(unsigned short, h)) << 16;
  return __builtin_bit_cast(float, u);
}

// async global->LDS, 16B per lane. lds base must be wave-uniform; HW scatters
// lane i's 16B to ldsbase + i*16.
__device__ inline void stage16(const __bf16* g, __bf16* l) {
  __builtin_amdgcn_global_load_lds(
      (const __attribute__((address_space(1))) unsigned int*)g,
      (__attribute__((address_space(3))) unsigned int*)l, 16, 0, 0);
}

// ---------------------------------------------------------------------------
// x (fp32) -> xhi + xlo (bf16 split).
// ---------------------------------------------------------------------------
__global__ __launch_bounds__(256) void cast_split(const float* __restrict__ in,
                                                  __bf16* __restrict__ hi,
                                                  __bf16* __restrict__ lo) {
  long i = (long)blockIdx.x * 256 + threadIdx.x;
  float f = in[i];
  __bf16 h = f2bf(f);
  hi[i] = h;
  lo[i] = f2bf(f - bf2f(h));
}

// ---------------------------------------------------------------------------
// W [D][DK] fp32 -> Wt hi/lo [DK][D] bf16 (transposed split). 32x32 LDS tile.
// ---------------------------------------------------------------------------
__global__ __launch_bounds__(256) void transpose_split(const float* __restrict__ in,
                                                       __bf16* __restrict__ hi,
                                                       __bf16* __restrict__ lo) {
  __shared__ float tile[32][33];
  int xI = blockIdx.x * 32 + threadIdx.x;
  int yI = blockIdx.y * 32 + threadIdx.y;
#pragma unroll
  for (int j = 0; j < 32; j += 8)
    tile[threadIdx.y + j][threadIdx.x] = in[(long)(yI + j) * DKc + xI];
  __syncthreads();
  int xO = blockIdx.y * 32 + threadIdx.x;
  int yO = blockIdx.x * 32 + threadIdx.y;
#pragma unroll
  for (int j = 0; j < 32; j += 8) {
    float v = tile[threadIdx.x][threadIdx.y + j];
    long idx = (long)(yO + j) * Dc + xO;
    __bf16 h = f2bf(v);
    hi[idx] = h;
    lo[idx] = f2bf(v - bf2f(h));
  }
}

// ---------------------------------------------------------------------------
// m97-structure NT MFMA GEMM: C[M][N] = A[M][K] * Bt[N][K]^T, row-major bf16.
// 128x128 block tile, 4 waves in 2x2, each wave 64x64 (4x4 accs of 16x16x32).
// BK=32 staged to LDS via global_load_lds width=16; ds_read_b128 frags.
// MODE_QK: split (3 MFMA), store bf16 hi+lo            (M=8192,N=1024,K=1024)
// MODE_V : plain, TRANSPOSED store via LDS -> Vt[b][n][seq]
// MODE_S : split, fp32 store * scale, z=B              (M=2048,N=2048,K=1024)
// MODE_PV: plain, fp32 store, z=B                      (M=2048,N=1024,K=2048)
// ---------------------------------------------------------------------------
enum { MODE_QK = 0, MODE_V = 1, MODE_S = 2, MODE_PV = 3 };

template <int MODE>
__global__ __launch_bounds__(256) void gemm_tile(
    const __bf16* __restrict__ Ahi, const __bf16* __restrict__ Alo,
    const __bf16* __restrict__ Bhi, const __bf16* __restrict__ Blo,
    float* __restrict__ Cf, __bf16* __restrict__ Chi, __bf16* __restrict__ Clo,
    float scale) {
  constexpr bool SPLIT = (MODE == MODE_QK || MODE == MODE_S);
  constexpr int  K = (MODE == MODE_PV) ? Sc : Dc;
  constexpr int  N = (MODE == MODE_S) ? Sc : DKc;
  constexpr long aBatch = (MODE == MODE_S) ? (long)Sc * DKc
                        : (MODE == MODE_PV) ? (long)Sc * Sc : 0;
  constexpr long bBatch = (MODE == MODE_S) ? (long)Sc * DKc
                        : (MODE == MODE_PV) ? (long)DKc * Sc : 0;
  constexpr long cBatch = (MODE == MODE_S) ? (long)Sc * Sc
                        : (MODE == MODE_PV) ? (long)Sc * DKc : 0;
  // LDS: staging tiles A/B (hi[+lo]) 8KB each; MODE_V reuses 32KB for the
  // transpose epilogue.
  constexpr int SMEM = (SPLIT || MODE == MODE_V) ? 32768 : 16384;
  __shared__ __align__(16) char smem[SMEM];
  __bf16* sAh = (__bf16*)smem;           // [128][32]
  __bf16* sBh = sAh + 128 * 32;
  __bf16* sAl = sBh + 128 * 32;          // split only
  __bf16* sBl = sAl + 128 * 32;

  const int b    = blockIdx.z;
  const int wave = threadIdx.x >> 6;
  const int lane = threadIdx.x & 63;
  const int wm   = wave >> 1;            // 0..1
  const int wn   = wave & 1;             // 0..1
  const int m0   = blockIdx.y * 128;
  const int n0   = blockIdx.x * 128;

  const __bf16* Ab  = Ahi + (long)b * aBatch + (long)m0 * K;
  const __bf16* Bb  = Bhi + (long)b * bBatch + (long)n0 * K;
  const __bf16* Abl = SPLIT ? Alo + (long)b * aBatch + (long)m0 * K : nullptr;
  const __bf16* Bbl = SPLIT ? Blo + (long)b * bBatch + (long)n0 * K : nullptr;

  // Staging geometry: wave w stages tile rows [w*32, w*32+32); lane covers
  // row = base + (lane>>2), col = (lane&3)*8. Flat LDS offset = base*32+lane*8
  // -> matches HW's base + lane*16B exactly (no padding allowed).
  const int sOffL = (lane >> 2) * 32 + (lane & 3) * 8;  // per-lane flat elems
  (void)sOffL;
  const int scol = (lane & 3) * 8;

  floatx4 acc[4][4];
  const floatx4 zero = {0.f, 0.f, 0.f, 0.f};
#pragma unroll
  for (int i = 0; i < 4; ++i)
#pragma unroll
    for (int j = 0; j < 4; ++j) acc[i][j] = zero;

  const int frow = lane & 15;
  const int koff = (lane >> 4) * 8;

#pragma unroll 1
  for (int k0 = 0; k0 < K; k0 += 32) {
#pragma unroll
    for (int i = 0; i < 2; ++i) {
      const int rb = wave * 32 + i * 16;            // wave-uniform row base
      const long go = (long)(rb + (lane >> 2)) * K + k0 + scol;
      stage16(Ab + go, sAh + rb * 32);
      stage16(Bb + go, sBh + rb * 32);
      if constexpr (SPLIT) {
        stage16(Abl + go, sAl + rb * 32);
        stage16(Bbl + go, sBl + rb * 32);
      }
    }
    __syncthreads();

    bf16x8 af[4], bfr[4], afl[4], bfl[4];
#pragma unroll
    for (int t = 0; t < 4; ++t) {
      af[t]  = *(const bf16x8*)(sAh + (wm * 64 + t * 16 + frow) * 32 + koff);
      bfr[t] = *(const bf16x8*)(sBh + (wn * 64 + t * 16 + frow) * 32 + koff);
      if constexpr (SPLIT) {
        afl[t] = *(const bf16x8*)(sAl + (wm * 64 + t * 16 + frow) * 32 + koff);
        bfl[t] = *(const bf16x8*)(sBl + (wn * 64 + t * 16 + frow) * 32 + koff);
      }
    }
#pragma unroll
    for (int mt = 0; mt < 4; ++mt)
#pragma unroll
      for (int nt = 0; nt < 4; ++nt) {
        acc[mt][nt] = __builtin_amdgcn_mfma_f32_16x16x32_bf16(af[mt], bfr[nt], acc[mt][nt], 0, 0, 0);
        if constexpr (SPLIT) {
          acc[mt][nt] = __builtin_amdgcn_mfma_f32_16x16x32_bf16(af[mt], bfl[nt], acc[mt][nt], 0, 0, 0);
          acc[mt][nt] = __builtin_amdgcn_mfma_f32_16x16x32_bf16(afl[mt], bfr[nt], acc[mt][nt], 0, 0, 0);
        }
      }
    __syncthreads();
  }

  // Epilogue. D layout: col=lane&15, row=(lane>>4)*4+reg (m89/m91-verified).
  const int crow0 = (lane >> 4) * 4;
  const int ccol  = lane & 15;

  if constexpr (MODE == MODE_V) {
    // Transpose through LDS (staging dead; reuse full 32KB as sT[128][128]).
    __bf16* sT = (__bf16*)smem;
#pragma unroll
    for (int nt = 0; nt < 4; ++nt) {
      int nl = wn * 64 + nt * 16 + ccol;
#pragma unroll
      for (int mt = 0; mt < 4; ++mt) {
        int ml = wm * 64 + mt * 16 + crow0;
#pragma unroll
        for (int r = 0; r < 4; ++r)
          sT[(long)nl * 128 + ml + r] = f2bf(acc[mt][nt][r]);
      }
    }
    __syncthreads();
    const int bb   = m0 >> 11;          // tile fully within one batch
    const int seq0 = m0 & (Sc - 1);
    __bf16* dst = Chi + (long)bb * DKc * Sc + seq0;
#pragma unroll
    for (int c = 0; c < 8; ++c) {
      int flat = c * 2048 + threadIdx.x * 8;   // elements; 16B per thread
      int row = flat >> 7, col = flat & 127;
      *(bf16x8*)(dst + (long)(n0 + row) * Sc + col) = *(const bf16x8*)(sT + flat);
    }
    return;
  }

#pragma unroll
  for (int nt = 0; nt < 4; ++nt) {
    int cn = n0 + wn * 64 + nt * 16 + ccol;
#pragma unroll
    for (int mt = 0; mt < 4; ++mt) {
#pragma unroll
      for (int r = 0; r < 4; ++r) {
        int cm = m0 + wm * 64 + mt * 16 + crow0 + r;
        float v = acc[mt][nt][r] * scale;
        if constexpr (MODE == MODE_S || MODE == MODE_PV) {
          Cf[(long)b * cBatch + (long)cm * N + cn] = v;
        } else {  // MODE_QK
          long idx = (long)cm * N + cn;
          __bf16 h = f2bf(v);
          Chi[idx] = h;
          Clo[idx] = f2bf(v - bf2f(h));
        }
      }
    }
  }
}

// ---------------------------------------------------------------------------
// Column softmax over q (axis=1) of scores[b][q][k], online max/sum.
// ---------------------------------------------------------------------------
__global__ __launch_bounds__(256) void softmax_col(const float* __restrict__ sc,
                                                   __bf16* __restrict__ attn) {
  __shared__ float sm[8][32], ss[8][32];
  const int b  = blockIdx.y;
  const int kk = threadIdx.x & 31;
  const int g  = threadIdx.x >> 5;
  const int k  = blockIdx.x * 32 + kk;
  const float* base = sc + (long)b * Sc * Sc + k;
  const int q0 = g * (Sc / 8), q1 = q0 + (Sc / 8);

  float m = -3.0e38f, s = 0.f;
  for (int q = q0; q < q1; ++q) {
    float v = base[(long)q * Sc];
    float mn = fmaxf(m, v);
    s = s * __expf(m - mn) + __expf(v - mn);
    m = mn;
  }
  sm[g][kk] = m;
  ss[g][kk] = s;
  __syncthreads();
  if (g == 0) {
    float M = sm[0][kk], S = ss[0][kk];
#pragma unroll
    for (int j = 1; j < 8; ++j) {
      float mj = sm[j][kk], sj = ss[j][kk];
      float mn = fmaxf(M, mj);
      S = S * __expf(M - mn) + sj * __expf(mj - mn);
      M = mn;
    }
    sm[0][kk] = M;
    ss[0][kk] = 1.0f / S;
  }
  __syncthreads();
  const float M = sm[0][kk], inv = ss[0][kk];
  __bf16* ab = attn + (long)b * Sc * Sc + k;
  for (int q = q0; q < q1; ++q) {
    float v = base[(long)q * Sc];
    ab[(long)q * Sc] = f2bf(__expf(v - M) * inv);
  }
}

// ---------------------------------------------------------------------------
extern "C" void kernel_launch(void* const* d_in, const int* in_sizes, int n_in,
                              void* d_out, int out_size, void* d_ws, size_t ws_size,
                              hipStream_t stream) {
  const float* x  = (const float*)d_in[0];
  const float* WQ = (const float*)d_in[1];
  const float* WK = (const float*)d_in[2];
  const float* WV = (const float*)d_in[3];
  float* out = (float*)d_out;
  char* ws = (char*)d_ws;
  const long MB = 1024L * 1024L;

  // Workspace layout (peak 188 MB). attn reuses the x region (x dead by then).
  __bf16* xhi  = (__bf16*)(ws + 0 * MB);     // 16 MB
  __bf16* xlo  = (__bf16*)(ws + 16 * MB);    // 16 MB
  __bf16* wqhi = (__bf16*)(ws + 32 * MB);    // 2 MB each
  __bf16* wqlo = (__bf16*)(ws + 34 * MB);
  __bf16* wkhi = (__bf16*)(ws + 36 * MB);
  __bf16* wklo = (__bf16*)(ws + 38 * MB);
  __bf16* wvhi = (__bf16*)(ws + 40 * MB);
  __bf16* wvlo = (__bf16*)(ws + 42 * MB);
  __bf16* qhi  = (__bf16*)(ws + 44 * MB);    // 16 MB each
  __bf16* qlo  = (__bf16*)(ws + 60 * MB);
  __bf16* khi  = (__bf16*)(ws + 76 * MB);
  __bf16* klo  = (__bf16*)(ws + 92 * MB);
  __bf16* vt   = (__bf16*)(ws + 108 * MB);   // 16 MB, [B][DK][S]
  float*  scs  = (float*)(ws + 124 * MB);    // 64 MB, [B][S][S]
  __bf16* attn = (__bf16*)(ws + 0 * MB);     // 32 MB, reuses x region

  cast_split<<<(int)((BSc * Dc) / 256), 256, 0, stream>>>(x, xhi, xlo);
  dim3 tb(32, 8);
  transpose_split<<<dim3(32, 32), tb, 0, stream>>>(WQ, wqhi, wqlo);
  transpose_split<<<dim3(32, 32), tb, 0, stream>>>(WK, wkhi, wklo);
  transpose_split<<<dim3(32, 32), tb, 0, stream>>>(WV, wvhi, wvlo);

  dim3 gProj(DKc / 128, BSc / 128, 1);
  gemm_tile<MODE_QK><<<gProj, 256, 0, stream>>>(xhi, xlo, wqhi, wqlo, nullptr, qhi, qlo, 1.0f);
  gemm_tile<MODE_QK><<<gProj, 256, 0, stream>>>(xhi, xlo, wkhi, wklo, nullptr, khi, klo, 1.0f);
  gemm_tile<MODE_V ><<<gProj, 256, 0, stream>>>(xhi, nullptr, wvhi, nullptr, nullptr, vt, nullptr, 1.0f);

  dim3 gS(Sc / 128, Sc / 128, Bc);
  gemm_tile<MODE_S><<<gS, 256, 0, stream>>>(qhi, qlo, khi, klo, scs, nullptr, nullptr, 0.03125f);

  softmax_col<<<dim3(Sc / 32, Bc), 256, 0, stream>>>(scs, attn);

  dim3 gPV(DKc / 128, Sc / 128, Bc);
  gemm_tile<MODE_PV><<<gPV, 256, 0, stream>>>(attn, nullptr, vt, nullptr, out, nullptr, nullptr, 1.0f);
}